// Round 6
// baseline (366.939 us; speedup 1.0000x reference)
//
#include <hip/hip_runtime.h>
#include <math.h>

#define VOCAB 32000
#define EMBED 200
#define HID   10
#define GATES 40
#define BSZ   256
#define SEQ   512
#define PF    8     // prefetch depth (steps ahead) for proj gathers
#define WPAD  204   // padded W_ih row stride in floats (16B-aligned, bank-spread)

__device__ __forceinline__ float rcp_fast(float x) { return __builtin_amdgcn_rcpf(x); }
__device__ __forceinline__ float sigmoid_fast(float x) {
    return rcp_fast(1.0f + __expf(-x));
}
__device__ __forceinline__ float readlane_f(float v, int l) {
    return __int_as_float(__builtin_amdgcn_readlane(__float_as_int(v), l));
}
// DPP quad_perm broadcast of quad-lane Q (pure VALU cross-lane, no LDS)
template <int Q>
__device__ __forceinline__ float quad_bcast(float v) {
    return __int_as_float(__builtin_amdgcn_mov_dpp(
        __float_as_int(v), Q * 0x55, 0xF, 0xF, true));
}

// ---------------------------------------------------------------------------
// Kernel A: proj[v][g] = dot(embed_W[v,:], W_ih[g,:]) + b_ih[g] + b_hh[g]
// 512 blocks x 256 thr (4 waves). W_ih staged to LDS coalesced once per
// block; each lane register-caches its gate row from LDS (cheap, one-time).
// Inner loop: wave-uniform embed float4 loads + 400 reg FMAs per vocab row.
// ---------------------------------------------------------------------------
__global__ __launch_bounds__(256, 2) void proj_kernel(
    const float* __restrict__ embed, const float* __restrict__ Wih,
    const float* __restrict__ bih,   const float* __restrict__ bhh,
    float* __restrict__ proj)
{
    __shared__ float ldsW[GATES * WPAD];
    const int tid = threadIdx.x;

    for (int idx = tid; idx < GATES * EMBED; idx += 256) {
        int g = idx / EMBED;
        int e = idx - g * EMBED;
        ldsW[g * WPAD + e] = Wih[idx];
    }
    __syncthreads();

    const int lane = tid & 63;
    const int wid  = tid >> 6;
    const int gl   = lane < GATES ? lane : GATES - 1;
    const float bias = bih[gl] + bhh[gl];

    float4 w[EMBED / 4];
    #pragma unroll
    for (int k = 0; k < EMBED / 4; ++k)
        w[k] = *(const float4*)&ldsW[gl * WPAD + 4 * k];

    for (int v = blockIdx.x * 4 + wid; v < VOCAB; v += gridDim.x * 4) {
        const float4* er = (const float4*)(embed + (size_t)v * EMBED);
        float a0 = 0.f, a1 = 0.f, a2 = 0.f, a3 = 0.f;
        #pragma unroll
        for (int k = 0; k < EMBED / 4; k += 2) {
            float4 e0 = er[k];     float4 w0 = w[k];
            float4 e1 = er[k + 1]; float4 w1 = w[k + 1];
            a0 = fmaf(e0.x, w0.x, a0); a1 = fmaf(e0.y, w0.y, a1);
            a2 = fmaf(e0.z, w0.z, a2); a3 = fmaf(e0.w, w0.w, a3);
            a0 = fmaf(e1.x, w1.x, a0); a1 = fmaf(e1.y, w1.y, a1);
            a2 = fmaf(e1.z, w1.z, a2); a3 = fmaf(e1.w, w1.w, a3);
        }
        if (lane < GATES)
            proj[v * GATES + lane] = (a0 + a1) + (a2 + a3) + bias;
    }
}

// ---------------------------------------------------------------------------
// Kernel B: recurrence, quad layout. lane = 4*j + k, j = hidden unit (0..9),
// k = gate class (0:i 1:f 2:g 3:o); gate row = k*10+j. Every lane redundantly
// maintains c/h for its unit j, so the i/f/g/o gather is 4 DPP quad
// broadcasts (VALU-only) and the h broadcast is 10 v_readlane into SGPRs
// (no LDS round trips on the serial chain). proj gathers prefetched PF=8
// steps ahead. Math is order-identical to the R5-passing kernel.
// ---------------------------------------------------------------------------
__global__ __launch_bounds__(64) void lstm_rec(
    const int*   __restrict__ tok,  const float* __restrict__ proj,
    const float* __restrict__ h0,   const float* __restrict__ c0,
    const float* __restrict__ Whh,
    const float* __restrict__ W1,   const float* __restrict__ b1,
    const float* __restrict__ lng,  const float* __restrict__ lnb,
    const float* __restrict__ W2,   const float* __restrict__ b2,
    float* __restrict__ out)
{
    __shared__ int tok_s[SEQ];

    const int b    = blockIdx.x;
    const int lane = threadIdx.x;
    const int j0   = min(lane >> 2, HID - 1);  // hidden unit
    const int k4   = lane & 3;                 // gate class i/f/g/o
    const int gate = k4 * HID + j0;            // row in [i|f|g|o]-major order

    #pragma unroll
    for (int k = 0; k < SEQ / 64; ++k)
        tok_s[k * 64 + lane] = tok[b * SEQ + k * 64 + lane];
    __syncthreads();

    // W_hh row for this gate
    float w[HID];
    #pragma unroll
    for (int j = 0; j < HID; ++j) w[j] = Whh[gate * HID + j];

    // h state as wave-uniform values (SGPR-resident after readlane updates)
    float hs[HID];
    #pragma unroll
    for (int u = 0; u < HID; ++u) hs[u] = h0[b * HID + u];
    // every lane redundantly carries c for its unit j0
    float c_own = c0[b * HID + j0];

    // tanh-vs-sigmoid multiplier: gate class 2 (g) computes tanh
    const float am  = (k4 == 2) ? 2.f : 1.f;
    const float amc = 1.f - am;

    // ---- prefetch pipeline init ----
    float gx_ring[PF];
    int   t2_ring[PF];
    #pragma unroll
    for (int k = 0; k < PF; ++k) {
        gx_ring[k] = proj[tok_s[k] * GATES + gate];
        t2_ring[k] = tok_s[k + PF];
    }

    for (int s0 = 0; s0 < SEQ; s0 += PF) {
        #pragma unroll
        for (int k = 0; k < PF; ++k) {
            float gx = gx_ring[k];
            gx_ring[k] = proj[t2_ring[k] * GATES + gate];
            int idx = s0 + k + 2 * PF;
            t2_ring[k] = tok_s[idx < SEQ ? idx : 0];

            // gates = gx + h . Whh_row  (two independent FMA chains)
            float a0 = gx, a1 = 0.f;
            a0 = fmaf(hs[0], w[0], a0); a1 = fmaf(hs[1], w[1], a1);
            a0 = fmaf(hs[2], w[2], a0); a1 = fmaf(hs[3], w[3], a1);
            a0 = fmaf(hs[4], w[4], a0); a1 = fmaf(hs[5], w[5], a1);
            a0 = fmaf(hs[6], w[6], a0); a1 = fmaf(hs[7], w[7], a1);
            a0 = fmaf(hs[8], w[8], a0); a1 = fmaf(hs[9], w[9], a1);
            float acc = a0 + a1;

            // branchless sigmoid/tanh: val = am*sigmoid(am*acc) + (1-am)
            float sg  = sigmoid_fast(am * acc);
            float val = fmaf(am, sg, amc);

            // i,f,g,o via DPP quad broadcasts (no LDS)
            float iv = quad_bcast<0>(val);
            float fv = quad_bcast<1>(val);
            float gv = quad_bcast<2>(val);
            float ov = quad_bcast<3>(val);

            c_own = fmaf(fv, c_own, iv * gv);                         // c = f*c + i*g
            float th    = fmaf(2.f, sigmoid_fast(2.f * c_own), -1.f); // tanh(c)
            float h_own = ov * th;

            // h broadcast: unit u lives in lane 4u -> readlane (SGPR, no LDS)
            hs[0] = readlane_f(h_own, 0);  hs[1] = readlane_f(h_own, 4);
            hs[2] = readlane_f(h_own, 8);  hs[3] = readlane_f(h_own, 12);
            hs[4] = readlane_f(h_own, 16); hs[5] = readlane_f(h_own, 20);
            hs[6] = readlane_f(h_own, 24); hs[7] = readlane_f(h_own, 28);
            hs[8] = readlane_f(h_own, 32); hs[9] = readlane_f(h_own, 36);
        }
    }

    // head: z = hn@W1^T + b1 ; LayerNorm(5) ; sigmoid(z@W2^T + b2)
    if (lane == 0) {
        float z[5];
        float mu = 0.f;
        #pragma unroll
        for (int m = 0; m < 5; ++m) {
            float a = b1[m];
            #pragma unroll
            for (int j = 0; j < HID; ++j) a = fmaf(hs[j], W1[m * HID + j], a);
            z[m] = a; mu += a;
        }
        mu *= 0.2f;
        float var = 0.f;
        #pragma unroll
        for (int m = 0; m < 5; ++m) { float d = z[m] - mu; var = fmaf(d, d, var); }
        var *= 0.2f;
        float rs = rsqrtf(var + 1e-5f);
        float acc = b2[0];
        #pragma unroll
        for (int m = 0; m < 5; ++m) {
            float zn = fmaf((z[m] - mu) * rs, lng[m], lnb[m]);
            acc = fmaf(zn, W2[m], acc);
        }
        out[b] = 1.f / (1.f + __expf(-acc));
    }
}

extern "C" void kernel_launch(void* const* d_in, const int* in_sizes, int n_in,
                              void* d_out, int out_size, void* d_ws, size_t ws_size,
                              hipStream_t stream) {
    const int*   tok   = (const int*)  d_in[0];
    const float* h0    = (const float*)d_in[1];
    const float* c0    = (const float*)d_in[2];
    const float* embed = (const float*)d_in[3];
    const float* Wih   = (const float*)d_in[4];
    const float* Whh   = (const float*)d_in[5];
    const float* bih   = (const float*)d_in[6];
    const float* bhh   = (const float*)d_in[7];
    const float* W1    = (const float*)d_in[8];
    const float* b1    = (const float*)d_in[9];
    const float* lng   = (const float*)d_in[10];
    const float* lnb   = (const float*)d_in[11];
    const float* W2    = (const float*)d_in[12];
    const float* b2    = (const float*)d_in[13];
    float* out  = (float*)d_out;
    float* proj = (float*)d_ws;   // VOCAB*GATES*4 = 5.12 MB

    hipLaunchKernelGGL(proj_kernel, dim3(512), dim3(256), 0, stream,
                       embed, Wih, bih, bhh, proj);
    hipLaunchKernelGGL(lstm_rec, dim3(BSZ), dim3(64), 0, stream,
                       tok, proj, h0, c0, Whh, W1, b1, lng, lnb, W2, b2, out);
}

// Round 7
// 123.486 us; speedup vs baseline: 2.9715x; 2.9715x over previous
//
#include <hip/hip_runtime.h>
#include <math.h>

#define VOCAB 32000
#define EMBED 200
#define HID   10
#define GATES 40
#define BSZ   256
#define SEQ   512
#define PF    8     // prefetch depth (steps ahead) for proj gathers

#define RPB   128   // vocab rows per block in proj GEMM
#define KCH   8     // K-chunk (EMBED=200 = 25 chunks exactly)

__device__ __forceinline__ float rcp_fast(float x) { return __builtin_amdgcn_rcpf(x); }
__device__ __forceinline__ float sigmoid_fast(float x) {
    return rcp_fast(1.0f + __expf(-x));
}
__device__ __forceinline__ float readlane_f(float v, int l) {
    return __int_as_float(__builtin_amdgcn_readlane(__float_as_int(v), l));
}
// DPP quad_perm broadcast of quad-lane Q (pure VALU cross-lane, no LDS)
template <int Q>
__device__ __forceinline__ float quad_bcast(float v) {
    return __int_as_float(__builtin_amdgcn_mov_dpp(
        __float_as_int(v), Q * 0x55, 0xF, 0xF, true));
}

// ---------------------------------------------------------------------------
// Kernel A: tiled fp32 GEMM  proj[v][g] = embed[v,:] . Wih[g,:] + bias[g].
// 250 blocks x 256 threads; 128 rows x 40 gates per block. W transposed in
// LDS [k][40] (32 KB, staged once); embed chunk [128][KCH] staged per k-chunk
// (pad 9 -> 9*tr mod 32 bijective, conflict-free). Thread tile: 4 rows x 5
// gates in registers (~50 VGPR, no spill -- the R6 spill was the 368 MB).
// ---------------------------------------------------------------------------
__global__ __launch_bounds__(256) void proj_kernel(
    const float* __restrict__ embed, const float* __restrict__ Wih,
    const float* __restrict__ bih,   const float* __restrict__ bhh,
    float* __restrict__ proj)
{
    __shared__ float wT[EMBED * GATES];          // [k][g]  32 KB
    __shared__ float eT[RPB * (KCH + 1)];        // [row][kk] padded

    const int tid = threadIdx.x;

    // stage W transposed (coalesced global read)
    for (int idx = tid; idx < GATES * EMBED; idx += 256) {
        int g = idx / EMBED, k = idx - g * EMBED;
        wT[k * GATES + g] = Wih[idx];
    }

    const int tr = tid & 31;        // row sub-index (0..31)
    const int tg = tid >> 5;        // gate group (0..7), 5 gates each
    const int v0 = blockIdx.x * RPB;

    float acc[4][5] = {{0.f}};

    for (int k0 = 0; k0 < EMBED; k0 += KCH) {
        __syncthreads();            // eT reuse from prev chunk + wT first use
        {
            int r  = tid >> 3;      // 0..31
            int kk = tid & 7;
            #pragma unroll
            for (int p = 0; p < 4; ++p) {
                int row = r + 32 * p;
                eT[row * (KCH + 1) + kk] =
                    embed[(size_t)(v0 + row) * EMBED + k0 + kk];
            }
        }
        __syncthreads();

        #pragma unroll
        for (int kk = 0; kk < KCH; ++kk) {
            float e0 = eT[(tr     ) * (KCH + 1) + kk];
            float e1 = eT[(tr + 32) * (KCH + 1) + kk];
            float e2 = eT[(tr + 64) * (KCH + 1) + kk];
            float e3 = eT[(tr + 96) * (KCH + 1) + kk];
            const float* wr = &wT[(k0 + kk) * GATES + tg * 5];
            float w0 = wr[0], w1 = wr[1], w2 = wr[2], w3 = wr[3], w4 = wr[4];
            acc[0][0] = fmaf(e0, w0, acc[0][0]);
            acc[0][1] = fmaf(e0, w1, acc[0][1]);
            acc[0][2] = fmaf(e0, w2, acc[0][2]);
            acc[0][3] = fmaf(e0, w3, acc[0][3]);
            acc[0][4] = fmaf(e0, w4, acc[0][4]);
            acc[1][0] = fmaf(e1, w0, acc[1][0]);
            acc[1][1] = fmaf(e1, w1, acc[1][1]);
            acc[1][2] = fmaf(e1, w2, acc[1][2]);
            acc[1][3] = fmaf(e1, w3, acc[1][3]);
            acc[1][4] = fmaf(e1, w4, acc[1][4]);
            acc[2][0] = fmaf(e2, w0, acc[2][0]);
            acc[2][1] = fmaf(e2, w1, acc[2][1]);
            acc[2][2] = fmaf(e2, w2, acc[2][2]);
            acc[2][3] = fmaf(e2, w3, acc[2][3]);
            acc[2][4] = fmaf(e2, w4, acc[2][4]);
            acc[3][0] = fmaf(e3, w0, acc[3][0]);
            acc[3][1] = fmaf(e3, w1, acc[3][1]);
            acc[3][2] = fmaf(e3, w2, acc[3][2]);
            acc[3][3] = fmaf(e3, w3, acc[3][3]);
            acc[3][4] = fmaf(e3, w4, acc[3][4]);
        }
    }

    // epilogue: add bias, write out
    float bb[5];
    #pragma unroll
    for (int j = 0; j < 5; ++j) {
        int g = tg * 5 + j;
        bb[j] = bih[g] + bhh[g];
    }
    #pragma unroll
    for (int i = 0; i < 4; ++i) {
        int v = v0 + tr + 32 * i;
        #pragma unroll
        for (int j = 0; j < 5; ++j)
            proj[v * GATES + tg * 5 + j] = acc[i][j] + bb[j];
    }
}

// ---------------------------------------------------------------------------
// Kernel B: recurrence, quad layout (UNCHANGED from R6, which passed).
// lane = 4*j + k, j = hidden unit (0..9), k = gate class (0:i 1:f 2:g 3:o);
// gate row = k*10+j. i/f/g/o gather = 4 DPP quad broadcasts; h broadcast =
// 10 v_readlane into SGPRs. proj gathers prefetched PF=8 steps ahead.
// ---------------------------------------------------------------------------
__global__ __launch_bounds__(64) void lstm_rec(
    const int*   __restrict__ tok,  const float* __restrict__ proj,
    const float* __restrict__ h0,   const float* __restrict__ c0,
    const float* __restrict__ Whh,
    const float* __restrict__ W1,   const float* __restrict__ b1,
    const float* __restrict__ lng,  const float* __restrict__ lnb,
    const float* __restrict__ W2,   const float* __restrict__ b2,
    float* __restrict__ out)
{
    __shared__ int tok_s[SEQ];

    const int b    = blockIdx.x;
    const int lane = threadIdx.x;
    const int j0   = min(lane >> 2, HID - 1);  // hidden unit
    const int k4   = lane & 3;                 // gate class i/f/g/o
    const int gate = k4 * HID + j0;            // row in [i|f|g|o]-major order

    #pragma unroll
    for (int k = 0; k < SEQ / 64; ++k)
        tok_s[k * 64 + lane] = tok[b * SEQ + k * 64 + lane];
    __syncthreads();

    // W_hh row for this gate
    float w[HID];
    #pragma unroll
    for (int j = 0; j < HID; ++j) w[j] = Whh[gate * HID + j];

    // h state as wave-uniform values
    float hs[HID];
    #pragma unroll
    for (int u = 0; u < HID; ++u) hs[u] = h0[b * HID + u];
    // every lane redundantly carries c for its unit j0
    float c_own = c0[b * HID + j0];

    // tanh-vs-sigmoid multiplier: gate class 2 (g) computes tanh
    const float am  = (k4 == 2) ? 2.f : 1.f;
    const float amc = 1.f - am;

    // ---- prefetch pipeline init ----
    float gx_ring[PF];
    int   t2_ring[PF];
    #pragma unroll
    for (int k = 0; k < PF; ++k) {
        gx_ring[k] = proj[tok_s[k] * GATES + gate];
        t2_ring[k] = tok_s[k + PF];
    }

    for (int s0 = 0; s0 < SEQ; s0 += PF) {
        #pragma unroll
        for (int k = 0; k < PF; ++k) {
            float gx = gx_ring[k];
            gx_ring[k] = proj[t2_ring[k] * GATES + gate];
            int idx = s0 + k + 2 * PF;
            t2_ring[k] = tok_s[idx < SEQ ? idx : 0];

            // gates = gx + h . Whh_row  (two independent FMA chains)
            float a0 = gx, a1 = 0.f;
            a0 = fmaf(hs[0], w[0], a0); a1 = fmaf(hs[1], w[1], a1);
            a0 = fmaf(hs[2], w[2], a0); a1 = fmaf(hs[3], w[3], a1);
            a0 = fmaf(hs[4], w[4], a0); a1 = fmaf(hs[5], w[5], a1);
            a0 = fmaf(hs[6], w[6], a0); a1 = fmaf(hs[7], w[7], a1);
            a0 = fmaf(hs[8], w[8], a0); a1 = fmaf(hs[9], w[9], a1);
            float acc = a0 + a1;

            // branchless sigmoid/tanh: val = am*sigmoid(am*acc) + (1-am)
            float sg  = sigmoid_fast(am * acc);
            float val = fmaf(am, sg, amc);

            // i,f,g,o via DPP quad broadcasts (no LDS)
            float iv = quad_bcast<0>(val);
            float fv = quad_bcast<1>(val);
            float gv = quad_bcast<2>(val);
            float ov = quad_bcast<3>(val);

            c_own = fmaf(fv, c_own, iv * gv);                         // c = f*c + i*g
            float th    = fmaf(2.f, sigmoid_fast(2.f * c_own), -1.f); // tanh(c)
            float h_own = ov * th;

            // h broadcast: unit u lives in lane 4u -> readlane (SGPR, no LDS)
            hs[0] = readlane_f(h_own, 0);  hs[1] = readlane_f(h_own, 4);
            hs[2] = readlane_f(h_own, 8);  hs[3] = readlane_f(h_own, 12);
            hs[4] = readlane_f(h_own, 16); hs[5] = readlane_f(h_own, 20);
            hs[6] = readlane_f(h_own, 24); hs[7] = readlane_f(h_own, 28);
            hs[8] = readlane_f(h_own, 32); hs[9] = readlane_f(h_own, 36);
        }
    }

    // head: z = hn@W1^T + b1 ; LayerNorm(5) ; sigmoid(z@W2^T + b2)
    if (lane == 0) {
        float z[5];
        float mu = 0.f;
        #pragma unroll
        for (int m = 0; m < 5; ++m) {
            float a = b1[m];
            #pragma unroll
            for (int j = 0; j < HID; ++j) a = fmaf(hs[j], W1[m * HID + j], a);
            z[m] = a; mu += a;
        }
        mu *= 0.2f;
        float var = 0.f;
        #pragma unroll
        for (int m = 0; m < 5; ++m) { float d = z[m] - mu; var = fmaf(d, d, var); }
        var *= 0.2f;
        float rs = rsqrtf(var + 1e-5f);
        float acc = b2[0];
        #pragma unroll
        for (int m = 0; m < 5; ++m) {
            float zn = fmaf((z[m] - mu) * rs, lng[m], lnb[m]);
            acc = fmaf(zn, W2[m], acc);
        }
        out[b] = 1.f / (1.f + __expf(-acc));
    }
}

extern "C" void kernel_launch(void* const* d_in, const int* in_sizes, int n_in,
                              void* d_out, int out_size, void* d_ws, size_t ws_size,
                              hipStream_t stream) {
    const int*   tok   = (const int*)  d_in[0];
    const float* h0    = (const float*)d_in[1];
    const float* c0    = (const float*)d_in[2];
    const float* embed = (const float*)d_in[3];
    const float* Wih   = (const float*)d_in[4];
    const float* Whh   = (const float*)d_in[5];
    const float* bih   = (const float*)d_in[6];
    const float* bhh   = (const float*)d_in[7];
    const float* W1    = (const float*)d_in[8];
    const float* b1    = (const float*)d_in[9];
    const float* lng   = (const float*)d_in[10];
    const float* lnb   = (const float*)d_in[11];
    const float* W2    = (const float*)d_in[12];
    const float* b2    = (const float*)d_in[13];
    float* out  = (float*)d_out;
    float* proj = (float*)d_ws;   // VOCAB*GATES*4 = 5.12 MB

    hipLaunchKernelGGL(proj_kernel, dim3(VOCAB / RPB), dim3(256), 0, stream,
                       embed, Wih, bih, bhh, proj);
    hipLaunchKernelGGL(lstm_rec, dim3(BSZ), dim3(64), 0, stream,
                       tok, proj, h0, c0, Whh, W1, b1, lng, lnb, W2, b2, out);
}

// Round 8
// 95.855 us; speedup vs baseline: 3.8281x; 1.2883x over previous
//
#include <hip/hip_runtime.h>
#include <math.h>

#define VOCAB 32000
#define EMBED 200
#define HID   10
#define GATES 40
#define BSZ   256
#define SEQ   512
#define PF    8     // steps per prefetch block

#define RPB   64    // vocab rows per block in proj GEMM
#define KCH   8     // K-chunk (EMBED = 25 chunks of 8 exactly)
#define WROW  48    // padded wT row stride (4 groups x 12, keeps 16B alignment)

__device__ __forceinline__ float rcp_fast(float x) { return __builtin_amdgcn_rcpf(x); }
__device__ __forceinline__ float exp2_fast(float x) { return __builtin_amdgcn_exp2f(x); }
__device__ __forceinline__ float readlane_f(float v, int l) {
    return __int_as_float(__builtin_amdgcn_readlane(__float_as_int(v), l));
}
// DPP quad_perm broadcast of quad-lane Q (pure VALU cross-lane, no LDS)
template <int Q>
__device__ __forceinline__ float quad_bcast(float v) {
    return __int_as_float(__builtin_amdgcn_mov_dpp(
        __float_as_int(v), Q * 0x55, 0xF, 0xF, true));
}

// ---------------------------------------------------------------------------
// Kernel A: tiled fp32 GEMM  proj[v][g] = embed[v,:] . Wih[g,:] + bias[g].
// 500 blocks x 256 thr (2 blocks/CU). Thread = 1 vocab row x 10 gates.
// wT[k][48] in LDS: each 16-lane gate-group reads the SAME address ->
// broadcast, no conflicts, b128-aligned (group stride 12 floats). eT row
// stride 9 -> worst 2-way conflict (free). 10 FMAs per k per thread,
// acc in 10 registers (no spill).
// ---------------------------------------------------------------------------
__global__ __launch_bounds__(256) void proj_kernel(
    const float* __restrict__ embed, const float* __restrict__ Wih,
    const float* __restrict__ bih,   const float* __restrict__ bhh,
    float* __restrict__ proj)
{
    __shared__ float wT[EMBED * WROW];        // 37.5 KB
    __shared__ float eT[RPB * (KCH + 1)];     // 2.25 KB

    const int tid = threadIdx.x;
    const int tr  = tid & 63;                 // vocab row within block
    const int tg  = tid >> 6;                 // gate group (0..3), 10 gates
    const int v0  = blockIdx.x * RPB;

    // stage W transposed+padded: wT[k][tg*12 + i] = Wih[(tg*10+i)*EMBED + k]
    for (int idx = tid; idx < GATES * EMBED; idx += 256) {
        int g = idx / EMBED, k = idx - g * EMBED;
        wT[k * WROW + (g / 10) * 12 + (g % 10)] = Wih[idx];
    }

    float acc[10];
    #pragma unroll
    for (int i = 0; i < 10; ++i) acc[i] = 0.f;

    for (int k0 = 0; k0 < EMBED; k0 += KCH) {
        __syncthreads();                      // eT reuse guard (+wT 1st iter)
        {
            int idx0 = tid;                   // stage 512 floats with 256 thr
            int r0 = idx0 >> 3, c0 = idx0 & 7;
            eT[r0 * (KCH + 1) + c0] = embed[(size_t)(v0 + r0) * EMBED + k0 + c0];
            int idx1 = tid + 256;
            int r1 = idx1 >> 3, c1 = idx1 & 7;
            eT[r1 * (KCH + 1) + c1] = embed[(size_t)(v0 + r1) * EMBED + k0 + c1];
        }
        __syncthreads();

        #pragma unroll
        for (int kk = 0; kk < KCH; ++kk) {
            float e = eT[tr * (KCH + 1) + kk];
            const float* wr = &wT[(k0 + kk) * WROW + tg * 12];
            float4 wa = *(const float4*)(wr);
            float4 wb = *(const float4*)(wr + 4);
            float2 wc = *(const float2*)(wr + 8);
            acc[0] = fmaf(e, wa.x, acc[0]);
            acc[1] = fmaf(e, wa.y, acc[1]);
            acc[2] = fmaf(e, wa.z, acc[2]);
            acc[3] = fmaf(e, wa.w, acc[3]);
            acc[4] = fmaf(e, wb.x, acc[4]);
            acc[5] = fmaf(e, wb.y, acc[5]);
            acc[6] = fmaf(e, wb.z, acc[6]);
            acc[7] = fmaf(e, wb.w, acc[7]);
            acc[8] = fmaf(e, wc.x, acc[8]);
            acc[9] = fmaf(e, wc.y, acc[9]);
        }
    }

    // epilogue: bias + float2 stores (all offsets 8B-aligned)
    const int gbase = tg * 10;
    float* op = &proj[(size_t)(v0 + tr) * GATES + gbase];
    #pragma unroll
    for (int i = 0; i < 5; ++i) {
        float2 o;
        o.x = acc[2 * i]     + bih[gbase + 2 * i]     + bhh[gbase + 2 * i];
        o.y = acc[2 * i + 1] + bih[gbase + 2 * i + 1] + bhh[gbase + 2 * i + 1];
        *(float2*)(op + 2 * i) = o;
    }
}

// ---------------------------------------------------------------------------
// Kernel B: recurrence, quad layout + clustered prefetch. lane = 4*j + k,
// j = hidden unit, k = gate class (0:i 1:f 2:g 3:o), gate row = k*10+j.
// Per 8-step block: issue 8 proj gathers (tokens read one block ago) + 8
// token LDS reads, then 8 pure-VALU steps: dot -> exp2 sigmoid/tanh ->
// 4 DPP quad broadcasts -> c update -> tanh -> 10 readlane h broadcast.
// No memory ops inside the serial 8-step run.
// ---------------------------------------------------------------------------
__global__ __launch_bounds__(64) void lstm_rec(
    const int*   __restrict__ tok,  const float* __restrict__ proj,
    const float* __restrict__ h0,   const float* __restrict__ c0,
    const float* __restrict__ Whh,
    const float* __restrict__ W1,   const float* __restrict__ b1,
    const float* __restrict__ lng,  const float* __restrict__ lnb,
    const float* __restrict__ W2,   const float* __restrict__ b2,
    float* __restrict__ out)
{
    __shared__ int tok_s[SEQ + 2 * PF];

    const int b    = blockIdx.x;
    const int lane = threadIdx.x;
    const int j0   = min(lane >> 2, HID - 1);  // hidden unit
    const int k4   = lane & 3;                 // gate class i/f/g/o
    const int gate = k4 * HID + j0;            // row in [i|f|g|o]-major order

    #pragma unroll
    for (int k = 0; k < SEQ / 64; ++k)
        tok_s[k * 64 + lane] = tok[b * SEQ + k * 64 + lane];
    if (lane < 2 * PF) tok_s[SEQ + lane] = 0;  // tail pad: safe addresses
    __syncthreads();

    // W_hh row for this gate
    float w[HID];
    #pragma unroll
    for (int j = 0; j < HID; ++j) w[j] = Whh[gate * HID + j];

    // h state (wave-uniform after readlane), redundant c per quad
    float hs[HID];
    #pragma unroll
    for (int u = 0; u < HID; ++u) hs[u] = h0[b * HID + u];
    float c_own = c0[b * HID + j0];

    // activation constants: gate class 2 (g) computes tanh via 2*sig(2x)-1
    const float am  = (k4 == 2) ? 2.f : 1.f;
    const float amc = 1.f - am;
    const float amn = -1.442695041f * am;      // exp2 scale for sigmoid(am*x)

    // ---- prologue: block 0 gathers in flight, block 1 tokens in regs ----
    int   tk_cur[PF], tk_nxt[PF];
    float gx_cur[PF], gx_nxt[PF];
    #pragma unroll
    for (int k = 0; k < PF; ++k) tk_cur[k] = tok_s[k];
    #pragma unroll
    for (int k = 0; k < PF; ++k) gx_cur[k] = proj[tk_cur[k] * GATES + gate];
    #pragma unroll
    for (int k = 0; k < PF; ++k) tk_nxt[k] = tok_s[PF + k];

    for (int s0 = 0; s0 < SEQ; s0 += PF) {
        // issue next block's gathers (uses tokens read one block ago)
        #pragma unroll
        for (int k = 0; k < PF; ++k)
            gx_nxt[k] = proj[tk_nxt[k] * GATES + gate];
        // read tokens for block s0+2*PF (pad guarantees valid indices)
        #pragma unroll
        for (int k = 0; k < PF; ++k)
            tk_cur[k] = tok_s[s0 + 2 * PF + k];

        // 8 pure-VALU steps
        #pragma unroll
        for (int k = 0; k < PF; ++k) {
            float a0 = gx_cur[k], a1 = 0.f;
            a0 = fmaf(hs[0], w[0], a0); a1 = fmaf(hs[1], w[1], a1);
            a0 = fmaf(hs[2], w[2], a0); a1 = fmaf(hs[3], w[3], a1);
            a0 = fmaf(hs[4], w[4], a0); a1 = fmaf(hs[5], w[5], a1);
            a0 = fmaf(hs[6], w[6], a0); a1 = fmaf(hs[7], w[7], a1);
            a0 = fmaf(hs[8], w[8], a0); a1 = fmaf(hs[9], w[9], a1);
            float acc = a0 + a1;

            // val = am*sigmoid(am*acc) + (1-am)  (sigmoid via exp2, 1 mul)
            float t   = exp2_fast(amn * acc);
            float sg  = rcp_fast(1.f + t);
            float val = fmaf(am, sg, amc);

            // i,f,g,o via DPP quad broadcasts (no LDS)
            float iv = quad_bcast<0>(val);
            float fv = quad_bcast<1>(val);
            float gv = quad_bcast<2>(val);
            float ov = quad_bcast<3>(val);

            c_own = fmaf(fv, c_own, iv * gv);               // c = f*c + i*g
            float t2 = exp2_fast(c_own * -2.885390082f);    // exp(-2c)
            float th = fmaf(2.f, rcp_fast(1.f + t2), -1.f); // tanh(c)
            float h_own = ov * th;

            // h broadcast: unit u lives in lane 4u -> readlane (no LDS)
            hs[0] = readlane_f(h_own, 0);  hs[1] = readlane_f(h_own, 4);
            hs[2] = readlane_f(h_own, 8);  hs[3] = readlane_f(h_own, 12);
            hs[4] = readlane_f(h_own, 16); hs[5] = readlane_f(h_own, 20);
            hs[6] = readlane_f(h_own, 24); hs[7] = readlane_f(h_own, 28);
            hs[8] = readlane_f(h_own, 32); hs[9] = readlane_f(h_own, 36);
        }

        // rotate rings (register moves, off the dependence-critical path)
        #pragma unroll
        for (int k = 0; k < PF; ++k) {
            gx_cur[k] = gx_nxt[k];
            int tmp = tk_cur[k];
            tk_nxt[k] = tmp;
        }
    }

    // head: z = hn@W1^T + b1 ; LayerNorm(5) ; sigmoid(z@W2^T + b2)
    if (lane == 0) {
        float z[5];
        float mu = 0.f;
        #pragma unroll
        for (int m = 0; m < 5; ++m) {
            float a = b1[m];
            #pragma unroll
            for (int j = 0; j < HID; ++j) a = fmaf(hs[j], W1[m * HID + j], a);
            z[m] = a; mu += a;
        }
        mu *= 0.2f;
        float var = 0.f;
        #pragma unroll
        for (int m = 0; m < 5; ++m) { float d = z[m] - mu; var = fmaf(d, d, var); }
        var *= 0.2f;
        float rs = rsqrtf(var + 1e-5f);
        float acc = b2[0];
        #pragma unroll
        for (int m = 0; m < 5; ++m) {
            float zn = fmaf((z[m] - mu) * rs, lng[m], lnb[m]);
            acc = fmaf(zn, W2[m], acc);
        }
        out[b] = 1.f / (1.f + __expf(-acc));
    }
}

extern "C" void kernel_launch(void* const* d_in, const int* in_sizes, int n_in,
                              void* d_out, int out_size, void* d_ws, size_t ws_size,
                              hipStream_t stream) {
    const int*   tok   = (const int*)  d_in[0];
    const float* h0    = (const float*)d_in[1];
    const float* c0    = (const float*)d_in[2];
    const float* embed = (const float*)d_in[3];
    const float* Wih   = (const float*)d_in[4];
    const float* Whh   = (const float*)d_in[5];
    const float* bih   = (const float*)d_in[6];
    const float* bhh   = (const float*)d_in[7];
    const float* W1    = (const float*)d_in[8];
    const float* b1    = (const float*)d_in[9];
    const float* lng   = (const float*)d_in[10];
    const float* lnb   = (const float*)d_in[11];
    const float* W2    = (const float*)d_in[12];
    const float* b2    = (const float*)d_in[13];
    float* out  = (float*)d_out;
    float* proj = (float*)d_ws;   // VOCAB*GATES*4 = 5.12 MB

    hipLaunchKernelGGL(proj_kernel, dim3(VOCAB / RPB), dim3(256), 0, stream,
                       embed, Wih, bih, bhh, proj);
    hipLaunchKernelGGL(lstm_rec, dim3(BSZ), dim3(64), 0, stream,
                       tok, proj, h0, c0, Whh, W1, b1, lng, lnb, W2, b2, out);
}